// Round 8
// baseline (148.453 us; speedup 1.0000x reference)
//
#include <hip/hip_runtime.h>
#include <hip/hip_bf16.h>
#include <cstdint>

// Problem: B=8, N=1024, C=256, H=8, D=64.
// out[b,i,o] = sum_{h,d} V[b,i,h,d] * w[b,i,h] * Wout[o,h,d]
// w[b,i,h]   = sum_j exp(S_ij)/d_j ;  S = Q K^T / 8 ; d_j = sum_i exp(S_ij)
// Q stored pre-scaled by 0.125*log2(e) => exp(S/8) == exp2(Q'K^T).
//
// 3 kernels, all occupancy-tuned:
//  k_qkv : 1024 blocks (b x 16 mt x h), inline weight cvt, same-h co-XCD.
//  k_attw: 64*NSLICE blocks; block owns NSLICE-th of j (K resident in regs),
//          streams Q twice (d_j block-local, then partial w_i), double-buffered
//          LDS (1 barrier/tile). NSLICE=16 (4 blocks/CU) when ws allows.
//  k_out : 512 blocks, sums NSLICE w-partials, inline Wo cvt.
// Layouts: Qh/Kh/Vh=[b*8+h][i][d] bf16; Wgp=[slice][b*8+h][i] f32.

typedef __attribute__((ext_vector_type(8))) short bf16x8;
typedef __attribute__((ext_vector_type(4))) float f32x4;

#define EXP2(x) __builtin_amdgcn_exp2f(x)
#define MFMA(a, b, c) __builtin_amdgcn_mfma_f32_16x16x32_bf16((a), (b), (c), 0, 0, 0)
#define QSCALE 0.18033688011112042f

static __device__ __forceinline__ uint32_t pk2(float x, float y) {
  union { __hip_bfloat162 h; uint32_t u; } c;
  c.h = __float22bfloat162_rn(float2{x, y});
  return c.u;
}
static __device__ __forceinline__ short cvt1(float f) {
  union { __hip_bfloat16 h; short s; } c;
  c.h = __float2bfloat16(f);
  return c.s;
}
static __device__ __forceinline__ bf16x8 mk8(const float4& u, const float4& v) {
  union { bf16x8 b; uint32_t w[4]; } r;
  r.w[0] = pk2(u.x, u.y); r.w[1] = pk2(u.z, u.w);
  r.w[2] = pk2(v.x, v.y); r.w[3] = pk2(v.z, v.w);
  return r.b;
}

// ---------------------------------------------------------------------------
// K1: fused QKV projection. 1024 blocks x 256 thr (4 blocks/CU).
// Block: (h = hw&7 -> same XCD shares weight panel; b, mt of 64 rows).
// ---------------------------------------------------------------------------
__global__ __launch_bounds__(256, 4) void k_qkv(
    const float* __restrict__ F,  const float* __restrict__ Wq,
    const float* __restrict__ Wk, const float* __restrict__ Wv,
    short* __restrict__ Qh, short* __restrict__ Kh, short* __restrict__ Vh)
{
  __shared__ short Bs[3][64][72];
  const int hw = blockIdx.x, t = threadIdx.x;
  const int h   = hw & 7;
  const int idx = hw >> 3;       // 0..127
  const int b   = idx >> 4;      // 0..7
  const int mt  = idx & 15;      // 0..15
  const int n0 = h * 64, m0 = mt * 64;
  const int wv = t >> 6, l = t & 63, lo = l & 15, hi = l >> 4;

  // B prefetch (step 0): fp32 -> packed bf16 (coalesced along n).
  uint32_t pbp[6][4];
#pragma unroll
  for (int it = 0; it < 6; ++it) {
    int id2 = t + it * 256, m = id2 >> 9, rem = id2 & 511, c8 = rem >> 6, n = rem & 63;
    const float* W = (m == 0) ? Wq : (m == 1) ? Wk : Wv;
    float f[8];
#pragma unroll
    for (int j = 0; j < 8; ++j) f[j] = W[(size_t)(c8 * 8 + j) * 512 + n0 + n];
#pragma unroll
    for (int q = 0; q < 4; ++q) pbp[it][q] = pk2(f[2 * q], f[2 * q + 1]);
  }
  // A prefetch (step 0): each lane's own fragment row.
  const size_t arow = (size_t)(b * 1024 + m0 + wv * 16 + lo) * 256;
  float4 pa[4];
#pragma unroll
  for (int kk = 0; kk < 2; ++kk) {
    pa[kk * 2 + 0] = *(const float4*)(F + arow + kk * 32 + hi * 8);
    pa[kk * 2 + 1] = *(const float4*)(F + arow + kk * 32 + hi * 8 + 4);
  }

  f32x4 acc[3][4];
#pragma unroll
  for (int m = 0; m < 3; ++m)
#pragma unroll
    for (int j = 0; j < 4; ++j) acc[m][j] = (f32x4){0.f, 0.f, 0.f, 0.f};

  for (int s = 0; s < 4; ++s) {
    if (s) __syncthreads();
#pragma unroll
    for (int it = 0; it < 6; ++it) {
      int id2 = t + it * 256, m = id2 >> 9, rem = id2 & 511, c8 = rem >> 6, n = rem & 63;
      *(uint4*)&Bs[m][n][c8 * 8] = *(uint4*)pbp[it];
    }
    __syncthreads();

    bf16x8 a[2];
    a[0] = mk8(pa[0], pa[1]);
    a[1] = mk8(pa[2], pa[3]);

    if (s < 3) {
      const int k0 = (s + 1) * 64;
#pragma unroll
      for (int kk = 0; kk < 2; ++kk) {
        pa[kk * 2 + 0] = *(const float4*)(F + arow + k0 + kk * 32 + hi * 8);
        pa[kk * 2 + 1] = *(const float4*)(F + arow + k0 + kk * 32 + hi * 8 + 4);
      }
#pragma unroll
      for (int it = 0; it < 6; ++it) {
        int id2 = t + it * 256, m = id2 >> 9, rem = id2 & 511, c8 = rem >> 6, n = rem & 63;
        const float* W = (m == 0) ? Wq : (m == 1) ? Wk : Wv;
        float f[8];
#pragma unroll
        for (int j = 0; j < 8; ++j) f[j] = W[(size_t)(k0 + c8 * 8 + j) * 512 + n0 + n];
#pragma unroll
        for (int q = 0; q < 4; ++q) pbp[it][q] = pk2(f[2 * q], f[2 * q + 1]);
      }
    }

#pragma unroll
    for (int m = 0; m < 3; ++m)
#pragma unroll
      for (int kk = 0; kk < 2; ++kk)
#pragma unroll
        for (int fc = 0; fc < 4; ++fc) {
          bf16x8 bfr = *(const bf16x8*)&Bs[m][fc * 16 + lo][kk * 32 + hi * 8];
          acc[m][fc] = MFMA(a[kk], bfr, acc[m][fc]);
        }
  }

#pragma unroll
  for (int m = 0; m < 3; ++m) {
    short* O = (m == 0) ? Qh : (m == 1) ? Kh : Vh;
#pragma unroll
    for (int fc = 0; fc < 4; ++fc)
#pragma unroll
      for (int r = 0; r < 4; ++r) {
        int i = m0 + wv * 16 + hi * 4 + r;
        int d = fc * 16 + lo;
        float v = acc[m][fc][r];
        if (m == 0) v *= QSCALE;
        O[((size_t)(b * 8 + h) * 1024 + i) * 64 + d] = cvt1(v);
      }
  }
}

// ---------------------------------------------------------------------------
// K2: fused colsum+rowsum. 64*NSLICE blocks; JW = 1024/NSLICE j per block.
// K resident in regs (JW/16 strips/wave); Q streamed twice, dbuf LDS.
// ---------------------------------------------------------------------------
template <int NSLICE>
__global__ __launch_bounds__(256, 4) void k_attw(
    const short* __restrict__ Qh, const short* __restrict__ Kh,
    float* __restrict__ Wgp)
{
  constexpr int JW = 1024 / NSLICE;   // 64 (NSLICE=16) or 128 (NSLICE=8)
  constexpr int NS = JW / 16;         // strips per wave
  __shared__ short Ks[JW][72];
  __shared__ short Qs[2][64][72];
  __shared__ float Red[4 * JW];
  const int hw = blockIdx.x, t = threadIdx.x;
  const int xcd = hw & 7;
  const int idx = hw >> 3;
  const int bh  = xcd * 8 + idx / NSLICE;   // same-bh blocks co-XCD (share Q stream)
  const int jb  = idx % NSLICE;
  const size_t base = (size_t)bh * 65536;
  const int j0 = jb * JW;
  const int wv = t >> 6, l = t & 63, lo = l & 15, hi = l >> 4;

  // stage resident K slice
#pragma unroll
  for (int it = 0; it < JW / 32; ++it) {
    int id2 = t + it * 256, r = id2 >> 3, c8 = id2 & 7;
    *(int4*)&Ks[r][c8 * 8] = *(const int4*)(Kh + base + (size_t)(j0 + r) * 64 + c8 * 8);
  }
  int4 pq[2];
#pragma unroll
  for (int it = 0; it < 2; ++it) {
    int id2 = t + it * 256, r = id2 >> 3, c8 = id2 & 7;
    pq[it] = *(const int4*)(Qh + base + (size_t)r * 64 + c8 * 8);
  }
  __syncthreads();

  bf16x8 bk[NS][2];
#pragma unroll
  for (int js = 0; js < NS; ++js) {
    bk[js][0] = *(const bf16x8*)&Ks[js * 16 + lo][hi * 8];
    bk[js][1] = *(const bf16x8*)&Ks[js * 16 + lo][32 + hi * 8];
  }

  // -------- pass 1: d_j (block-local; column sums are j-local)
#pragma unroll
  for (int it = 0; it < 2; ++it) {          // write tile0, load tile1
    int id2 = t + it * 256, r = id2 >> 3, c8 = id2 & 7;
    *(int4*)&Qs[0][r][c8 * 8] = pq[it];
    pq[it] = *(const int4*)(Qh + base + (size_t)(64 + r) * 64 + c8 * 8);
  }
  float cs[NS];
#pragma unroll
  for (int js = 0; js < NS; ++js) cs[js] = 0.f;

  for (int tile = 0; tile < 16; ++tile) {
    __syncthreads();
    if (tile < 15) {
#pragma unroll
      for (int it = 0; it < 2; ++it) {
        int id2 = t + it * 256, r = id2 >> 3, c8 = id2 & 7;
        *(int4*)&Qs[(tile + 1) & 1][r][c8 * 8] = pq[it];
      }
      if (tile < 14) {
#pragma unroll
        for (int it = 0; it < 2; ++it) {
          int id2 = t + it * 256, r = id2 >> 3, c8 = id2 & 7;
          pq[it] = *(const int4*)(Qh + base + (size_t)((tile + 2) * 64 + r) * 64 + c8 * 8);
        }
      }
    }
    bf16x8 a0 = *(const bf16x8*)&Qs[tile & 1][wv * 16 + lo][hi * 8];
    bf16x8 a1 = *(const bf16x8*)&Qs[tile & 1][wv * 16 + lo][32 + hi * 8];
#pragma unroll
    for (int js = 0; js < NS; ++js) {
      f32x4 acc = (f32x4){0.f, 0.f, 0.f, 0.f};
      acc = MFMA(a0, bk[js][0], acc);
      acc = MFMA(a1, bk[js][1], acc);
#pragma unroll
      for (int r = 0; r < 4; ++r) cs[js] += EXP2(acc[r]);
    }
  }

#pragma unroll
  for (int js = 0; js < NS; ++js) {
    cs[js] += __shfl_xor(cs[js], 16, 64);
    cs[js] += __shfl_xor(cs[js], 32, 64);
  }
  if (hi == 0) {
#pragma unroll
    for (int js = 0; js < NS; ++js) Red[wv * JW + js * 16 + lo] = cs[js];
  }
  // reload tile0/tile1 for pass 2 (loads in flight across the barrier)
#pragma unroll
  for (int it = 0; it < 2; ++it) {
    int id2 = t + it * 256, r = id2 >> 3, c8 = id2 & 7;
    pq[it] = *(const int4*)(Qh + base + (size_t)r * 64 + c8 * 8);
  }
  __syncthreads();   // Red ready; pass-1 Qs reads done
  float rj[NS];
#pragma unroll
  for (int js = 0; js < NS; ++js) {
    int jj = js * 16 + lo;
    float d = Red[jj] + Red[JW + jj] + Red[2 * JW + jj] + Red[3 * JW + jj];
    rj[js] = __builtin_amdgcn_rcpf(d);
  }

  // -------- pass 2: partial w_i over this j-slice
#pragma unroll
  for (int it = 0; it < 2; ++it) {
    int id2 = t + it * 256, r = id2 >> 3, c8 = id2 & 7;
    *(int4*)&Qs[0][r][c8 * 8] = pq[it];
    pq[it] = *(const int4*)(Qh + base + (size_t)(64 + r) * 64 + c8 * 8);
  }
  for (int tile = 0; tile < 16; ++tile) {
    __syncthreads();
    if (tile < 15) {
#pragma unroll
      for (int it = 0; it < 2; ++it) {
        int id2 = t + it * 256, r = id2 >> 3, c8 = id2 & 7;
        *(int4*)&Qs[(tile + 1) & 1][r][c8 * 8] = pq[it];
      }
      if (tile < 14) {
#pragma unroll
        for (int it = 0; it < 2; ++it) {
          int id2 = t + it * 256, r = id2 >> 3, c8 = id2 & 7;
          pq[it] = *(const int4*)(Qh + base + (size_t)((tile + 2) * 64 + r) * 64 + c8 * 8);
        }
      }
    }
    bf16x8 a0 = *(const bf16x8*)&Qs[tile & 1][wv * 16 + lo][hi * 8];
    bf16x8 a1 = *(const bf16x8*)&Qs[tile & 1][wv * 16 + lo][32 + hi * 8];
    float ws4[4] = {0.f, 0.f, 0.f, 0.f};
#pragma unroll
    for (int js = 0; js < NS; ++js) {
      f32x4 acc = (f32x4){0.f, 0.f, 0.f, 0.f};
      acc = MFMA(a0, bk[js][0], acc);
      acc = MFMA(a1, bk[js][1], acc);
#pragma unroll
      for (int r = 0; r < 4; ++r) ws4[r] = fmaf(EXP2(acc[r]), rj[js], ws4[r]);
    }
#pragma unroll
    for (int m = 1; m <= 8; m <<= 1)
#pragma unroll
      for (int r = 0; r < 4; ++r) ws4[r] += __shfl_xor(ws4[r], m, 64);
    if (lo == 0) {
      float4 o = {ws4[0], ws4[1], ws4[2], ws4[3]};
      *(float4*)&Wgp[(size_t)jb * 65536 + (size_t)bh * 1024 +
                     tile * 64 + wv * 16 + hi * 4] = o;
    }
  }
}

// ---------------------------------------------------------------------------
// K3: out = (V .* w) @ Wo^T; w = sum of NSLICE partials. 512 blocks x 256.
// ---------------------------------------------------------------------------
template <int NSLICE>
__global__ __launch_bounds__(256, 2) void k_out(
    const short* __restrict__ Vh, const float* __restrict__ Wgp,
    const float* __restrict__ Wo, float* __restrict__ Out)
{
  __shared__ short As[64][72];
  __shared__ short Bs[64][72];
  const int hw = blockIdx.x, t = threadIdx.x;
  const int slot = hw >> 3;
  const int g    = (hw & 7) * 16 + (slot >> 2);
  const int nt   = slot & 3;
  const int b    = g >> 4;
  const int mt   = g & 15;
  const int n0   = nt * 64;
  const int m0   = mt * 64;
  const int wv = t >> 6, l = t & 63, lo = l & 15, hi = l >> 4;

  int4     pv[2];
  float    pws[2];
  uint32_t pbp[2][4];
#pragma unroll
  for (int it = 0; it < 2; ++it) {
    int id2 = t + it * 256, r = id2 >> 3, c8 = id2 & 7;
    pv[it] = *(const int4*)(Vh + ((size_t)(b * 8 + 0) * 1024 + m0 + r) * 64 + c8 * 8);
    size_t wo = (size_t)(b * 8 + 0) * 1024 + m0 + r;
    float sum = 0.f;
#pragma unroll
    for (int p = 0; p < NSLICE; ++p) sum += Wgp[(size_t)p * 65536 + wo];
    pws[it] = sum;
    const float* wp = Wo + (size_t)(n0 + r) * 512 + c8 * 8;
    float4 f0 = *(const float4*)(wp);
    float4 f1 = *(const float4*)(wp + 4);
    pbp[it][0] = pk2(f0.x, f0.y); pbp[it][1] = pk2(f0.z, f0.w);
    pbp[it][2] = pk2(f1.x, f1.y); pbp[it][3] = pk2(f1.z, f1.w);
  }

  f32x4 acc[4];
#pragma unroll
  for (int j = 0; j < 4; ++j) acc[j] = (f32x4){0.f, 0.f, 0.f, 0.f};

  for (int s = 0; s < 8; ++s) {
    if (s) __syncthreads();
#pragma unroll
    for (int it = 0; it < 2; ++it) {
      int id2 = t + it * 256, r = id2 >> 3, c8 = id2 & 7;
      uint32_t* u = (uint32_t*)&pv[it];
      float ws = pws[it];
      uint32_t o[4];
#pragma unroll
      for (int j = 0; j < 4; ++j) {
        float f0 = __uint_as_float(u[j] << 16) * ws;
        float f1 = __uint_as_float(u[j] & 0xffff0000u) * ws;
        o[j] = pk2(f0, f1);
      }
      *(uint4*)&As[r][c8 * 8] = *(uint4*)o;
      *(uint4*)&Bs[r][c8 * 8] = *(uint4*)pbp[it];
    }
    __syncthreads();
    if (s < 7) {
#pragma unroll
      for (int it = 0; it < 2; ++it) {
        int id2 = t + it * 256, r = id2 >> 3, c8 = id2 & 7;
        pv[it] = *(const int4*)(Vh + ((size_t)(b * 8 + s + 1) * 1024 + m0 + r) * 64 + c8 * 8);
        size_t wo = (size_t)(b * 8 + s + 1) * 1024 + m0 + r;
        float sum = 0.f;
#pragma unroll
        for (int p = 0; p < NSLICE; ++p) sum += Wgp[(size_t)p * 65536 + wo];
        pws[it] = sum;
        const float* wp = Wo + (size_t)(n0 + r) * 512 + (s + 1) * 64 + c8 * 8;
        float4 f0 = *(const float4*)(wp);
        float4 f1 = *(const float4*)(wp + 4);
        pbp[it][0] = pk2(f0.x, f0.y); pbp[it][1] = pk2(f0.z, f0.w);
        pbp[it][2] = pk2(f1.x, f1.y); pbp[it][3] = pk2(f1.z, f1.w);
      }
    }

#pragma unroll
    for (int kk = 0; kk < 2; ++kk) {
      bf16x8 a = *(const bf16x8*)&As[wv * 16 + lo][kk * 32 + hi * 8];
#pragma unroll
      for (int fc = 0; fc < 4; ++fc) {
        bf16x8 bfr = *(const bf16x8*)&Bs[fc * 16 + lo][kk * 32 + hi * 8];
        acc[fc] = MFMA(a, bfr, acc[fc]);
      }
    }
  }

#pragma unroll
  for (int fc = 0; fc < 4; ++fc)
#pragma unroll
    for (int r = 0; r < 4; ++r) {
      int i = m0 + wv * 16 + hi * 4 + r;
      int o = n0 + fc * 16 + lo;
      Out[(size_t)(b * 1024 + i) * 256 + o] = acc[fc][r];
    }
}

// ---------------------------------------------------------------------------
extern "C" void kernel_launch(void* const* d_in, const int* in_sizes, int n_in,
                              void* d_out, int out_size, void* d_ws, size_t ws_size,
                              hipStream_t stream) {
  const float* F  = (const float*)d_in[0];
  const float* Wq = (const float*)d_in[1];
  const float* Wk = (const float*)d_in[2];
  const float* Wv = (const float*)d_in[3];
  const float* Wo = (const float*)d_in[4];
  float* out = (float*)d_out;

  char* ws = (char*)d_ws;
  short* Qh  = (short*)(ws);                       // 8 MB bf16
  short* Kh  = (short*)(ws + (size_t)(8  << 20));  // 8 MB
  short* Vh  = (short*)(ws + (size_t)(16 << 20));  // 8 MB
  float* Wgp = (float*)(ws + (size_t)(24 << 20));  // up to 4 MB partials

  k_qkv<<<dim3(1024), 256, 0, stream>>>(F, Wq, Wk, Wv, Qh, Kh, Vh);

  // 16 slices need 24 MB + 4 MB of ws; fall back to 8 otherwise.
  if (ws_size >= ((size_t)28 << 20)) {
    k_attw<16><<<dim3(1024), 256, 0, stream>>>(Qh, Kh, Wgp);
    k_out<16> <<<dim3(512),  256, 0, stream>>>(Vh, Wgp, Wo, out);
  } else {
    k_attw<8> <<<dim3(512),  256, 0, stream>>>(Qh, Kh, Wgp);
    k_out<8>  <<<dim3(512),  256, 0, stream>>>(Vh, Wgp, Wo, out);
  }
}

// Round 10
// 101.676 us; speedup vs baseline: 1.4601x; 1.4601x over previous
//
#include <hip/hip_runtime.h>
#include <hip/hip_bf16.h>
#include <cstdint>

// Problem: B=8, N=1024, C=256, H=8, D=64.
// out[b,i,o] = sum_{h,d} V[b,i,h,d] * w[b,i,h] * Wout[o,h,d]
// w[b,i,h]   = sum_j exp(S_ij)/d_j ;  S = Q K^T / 8 ; d_j = sum_i exp(S_ij)
// Wq pre-scaled by 0.125*log2(e) in prep => exp(S/8) == exp2(Q'K^T).
//
// Barrier-free design: all MFMA fragments are loaded per-lane directly from
// global (L2-resident operands); no LDS staging loops.
//  k_prep: Wt[3][512][256] bf16 (transposed, Q-scaled) + Wob[256][512] bf16.
//  k_qkv : 512 blocks, 0 barriers. A from F (fp32->bf16 in regs), B from Wt.
//  k_attw: 512 blocks = (bh x 8 jb), K-slice resident in regs (bk[8][2]),
//          2 Q-stream passes, ONE barrier (cross-wave d_j reduce, 2KB LDS).
//  k_out : 512 blocks, w-partial sum in 2KB LDS prologue (one barrier),
//          A=(V.*w) built in regs, B from Wob.
// Layouts: Qh/Kh/Vh=[b*8+h][i][d] bf16; Wgp=[jb][b*8+h][i] f32.

typedef __attribute__((ext_vector_type(8))) short bf16x8;
typedef __attribute__((ext_vector_type(4))) float f32x4;

#define EXP2(x) __builtin_amdgcn_exp2f(x)
#define MFMA(a, b, c) __builtin_amdgcn_mfma_f32_16x16x32_bf16((a), (b), (c), 0, 0, 0)
#define QSCALE 0.18033688011112042f

static __device__ __forceinline__ uint32_t pk2(float x, float y) {
  union { __hip_bfloat162 h; uint32_t u; } c;
  c.h = __float22bfloat162_rn(float2{x, y});
  return c.u;
}
static __device__ __forceinline__ short cvt1(float f) {
  union { __hip_bfloat16 h; short s; } c;
  c.h = __float2bfloat16(f);
  return c.s;
}
static __device__ __forceinline__ bf16x8 mk8(const float4& u, const float4& v) {
  union { bf16x8 b; uint32_t w[4]; } r;
  r.w[0] = pk2(u.x, u.y); r.w[1] = pk2(u.z, u.w);
  r.w[2] = pk2(v.x, v.y); r.w[3] = pk2(v.z, v.w);
  return r.b;
}

// ---------------------------------------------------------------------------
// K0: weight prep. Wt[m][n][c] = bf16(W_m[c][n] * (m==0?QSCALE:1)),
// Wob[o][k] = bf16(Wo[o][k]). 256 blocks x 256.
// ---------------------------------------------------------------------------
__global__ __launch_bounds__(256) void k_prep(
    const float* __restrict__ Wq, const float* __restrict__ Wk,
    const float* __restrict__ Wv, const float* __restrict__ Wo,
    short* __restrict__ Wt, short* __restrict__ Wob)
{
  const int gt = blockIdx.x * 256 + threadIdx.x;
  if (gt < 49152) {
    const int m  = gt >> 14;
    const int r  = gt & 16383;
    const int n  = r >> 5;     // 0..511
    const int c8 = r & 31;     // c = c8*8
    const float* W = (m == 0) ? Wq : (m == 1) ? Wk : Wv;
    const float scale = (m == 0) ? QSCALE : 1.0f;
    short tmp[8];
#pragma unroll
    for (int j = 0; j < 8; ++j)
      tmp[j] = cvt1(W[(size_t)(c8 * 8 + j) * 512 + n] * scale);
    *(int4*)&Wt[(size_t)m * 131072 + n * 256 + c8 * 8] = *(int4*)tmp;
  } else if (gt < 65536) {
    const int r  = gt - 49152; // 0..16383
    const int o  = r >> 6;
    const int k8 = r & 63;
    const float4 v0 = *(const float4*)(Wo + (size_t)o * 512 + k8 * 8);
    const float4 v1 = *(const float4*)(Wo + (size_t)o * 512 + k8 * 8 + 4);
    uint32_t tmp[4] = {pk2(v0.x, v0.y), pk2(v0.z, v0.w),
                       pk2(v1.x, v1.y), pk2(v1.z, v1.w)};
    *(uint4*)&Wob[(size_t)o * 512 + k8 * 8] = *(uint4*)tmp;
  }
}

// ---------------------------------------------------------------------------
// K1: fused QKV projection. 512 blocks x 256, ZERO barriers / no LDS.
// Block: (h = hw&7 co-XCD shares Wt panel; b, mt of 128 rows).
// ---------------------------------------------------------------------------
__global__ __launch_bounds__(256, 2) void k_qkv(
    const float* __restrict__ F, const short* __restrict__ Wt,
    short* __restrict__ Qh, short* __restrict__ Kh, short* __restrict__ Vh)
{
  const int hw = blockIdx.x, t = threadIdx.x;
  const int h   = hw & 7;
  const int idx = hw >> 3;       // 0..63
  const int b   = idx >> 3;      // 0..7
  const int mt  = idx & 7;       // 0..7
  const int n0 = h * 64, m0 = mt * 128;
  const int wv = t >> 6, l = t & 63, lo = l & 15, hi = l >> 4;

  f32x4 acc[3][2][4];
#pragma unroll
  for (int m = 0; m < 3; ++m)
#pragma unroll
    for (int i = 0; i < 2; ++i)
#pragma unroll
      for (int j = 0; j < 4; ++j) acc[m][i][j] = (f32x4){0.f, 0.f, 0.f, 0.f};

  const float* arow0 = F + (size_t)(b * 1024 + m0 + wv * 32 + lo) * 256;
  const float* arow1 = F + (size_t)(b * 1024 + m0 + wv * 32 + 16 + lo) * 256;

#pragma unroll 1
  for (int s = 0; s < 4; ++s) {
    const int k0 = s * 64;
    // A fragments: fp32 -> bf16 in registers, per-lane loads
    bf16x8 a[2][2];
#pragma unroll
    for (int kk = 0; kk < 2; ++kk) {
      const int off = k0 + kk * 32 + hi * 8;
      a[0][kk] = mk8(*(const float4*)(arow0 + off), *(const float4*)(arow0 + off + 4));
      a[1][kk] = mk8(*(const float4*)(arow1 + off), *(const float4*)(arow1 + off + 4));
    }
    // B fragments per-lane from Wt (L2-hot, shared by co-XCD blocks)
#pragma unroll
    for (int m = 0; m < 3; ++m)
#pragma unroll
      for (int kk = 0; kk < 2; ++kk)
#pragma unroll
        for (int fc = 0; fc < 4; ++fc) {
          bf16x8 bfr = *(const bf16x8*)(Wt + (size_t)m * 131072 +
                         (size_t)(n0 + fc * 16 + lo) * 256 + k0 + kk * 32 + hi * 8);
          acc[m][0][fc] = MFMA(a[0][kk], bfr, acc[m][0][fc]);
          acc[m][1][fc] = MFMA(a[1][kk], bfr, acc[m][1][fc]);
        }
  }

#pragma unroll
  for (int m = 0; m < 3; ++m) {
    short* O = (m == 0) ? Qh : (m == 1) ? Kh : Vh;
#pragma unroll
    for (int fr = 0; fr < 2; ++fr)
#pragma unroll
      for (int fc = 0; fc < 4; ++fc)
#pragma unroll
        for (int r = 0; r < 4; ++r) {
          int i = m0 + wv * 32 + fr * 16 + hi * 4 + r;
          int d = fc * 16 + lo;
          O[((size_t)(b * 8 + h) * 1024 + i) * 64 + d] = cvt1(acc[m][fr][fc][r]);
        }
  }
}

// ---------------------------------------------------------------------------
// K2: fused colsum+rowsum. 512 blocks = (bh co-XCD) x 8 jb (128 j each).
// K-slice resident in regs; waves independently stream i-strips from global.
// ONE barrier total (cross-wave d_j reduce).
// ---------------------------------------------------------------------------
__global__ __launch_bounds__(256, 2) void k_attw(
    const short* __restrict__ Qh, const short* __restrict__ Kh,
    float* __restrict__ Wgp)
{
  __shared__ float Red[512];
  const int hw = blockIdx.x, t = threadIdx.x;
  const int xcd = hw & 7;
  const int idx = hw >> 3;              // 0..63
  const int bh  = xcd * 8 + (idx >> 3); // same-bh blocks co-XCD
  const int jb  = idx & 7;
  const size_t base = (size_t)bh * 65536;
  const int j0 = jb * 128;
  const int wv = t >> 6, l = t & 63, lo = l & 15, hi = l >> 4;

  // resident K fragments: 8 strips of 16 j per wave (all 128 j of the slice)
  bf16x8 bk[8][2];
#pragma unroll
  for (int js = 0; js < 8; ++js) {
    const short* kr = Kh + base + (size_t)(j0 + js * 16 + lo) * 64 + hi * 8;
    bk[js][0] = *(const bf16x8*)(kr);
    bk[js][1] = *(const bf16x8*)(kr + 32);
  }

  // -------- pass 1: d_j = sum_i exp2(S'_ij); wave wv does strips wv+4k
  float cs[8];
#pragma unroll
  for (int js = 0; js < 8; ++js) cs[js] = 0.f;

  {
    const short* q0 = Qh + base + (size_t)(wv * 16 + lo) * 64 + hi * 8;
    bf16x8 a0 = *(const bf16x8*)(q0);
    bf16x8 a1 = *(const bf16x8*)(q0 + 32);
#pragma unroll 1
    for (int k = 0; k < 16; ++k) {
      bf16x8 n0v = a0, n1v = a1;
      if (k < 15) {
        const short* qn = Qh + base + (size_t)((wv + 4 * (k + 1)) * 16 + lo) * 64 + hi * 8;
        n0v = *(const bf16x8*)(qn);
        n1v = *(const bf16x8*)(qn + 32);
      }
#pragma unroll
      for (int js = 0; js < 8; ++js) {
        f32x4 acc = (f32x4){0.f, 0.f, 0.f, 0.f};
        acc = MFMA(a0, bk[js][0], acc);
        acc = MFMA(a1, bk[js][1], acc);
#pragma unroll
        for (int r = 0; r < 4; ++r) cs[js] += EXP2(acc[r]);
      }
      a0 = n0v; a1 = n1v;
    }
  }

#pragma unroll
  for (int js = 0; js < 8; ++js) {
    cs[js] += __shfl_xor(cs[js], 16, 64);
    cs[js] += __shfl_xor(cs[js], 32, 64);
  }
  if (hi == 0) {
#pragma unroll
    for (int js = 0; js < 8; ++js) Red[wv * 128 + js * 16 + lo] = cs[js];
  }
  __syncthreads();   // the only barrier
  float rj[8];
#pragma unroll
  for (int js = 0; js < 8; ++js) {
    int jj = js * 16 + lo;
    float d = Red[jj] + Red[128 + jj] + Red[256 + jj] + Red[384 + jj];
    rj[js] = __builtin_amdgcn_rcpf(d);
  }

  // -------- pass 2: partial w_i over this j-slice
  {
    const short* q0 = Qh + base + (size_t)(wv * 16 + lo) * 64 + hi * 8;
    bf16x8 a0 = *(const bf16x8*)(q0);
    bf16x8 a1 = *(const bf16x8*)(q0 + 32);
#pragma unroll 1
    for (int k = 0; k < 16; ++k) {
      bf16x8 n0v = a0, n1v = a1;
      if (k < 15) {
        const short* qn = Qh + base + (size_t)((wv + 4 * (k + 1)) * 16 + lo) * 64 + hi * 8;
        n0v = *(const bf16x8*)(qn);
        n1v = *(const bf16x8*)(qn + 32);
      }
      float ws4[4] = {0.f, 0.f, 0.f, 0.f};
#pragma unroll
      for (int js = 0; js < 8; ++js) {
        f32x4 acc = (f32x4){0.f, 0.f, 0.f, 0.f};
        acc = MFMA(a0, bk[js][0], acc);
        acc = MFMA(a1, bk[js][1], acc);
#pragma unroll
        for (int r = 0; r < 4; ++r) ws4[r] = fmaf(EXP2(acc[r]), rj[js], ws4[r]);
      }
#pragma unroll
      for (int m = 1; m <= 8; m <<= 1)
#pragma unroll
        for (int r = 0; r < 4; ++r) ws4[r] += __shfl_xor(ws4[r], m, 64);
      if (lo == 0) {
        float4 o = {ws4[0], ws4[1], ws4[2], ws4[3]};
        *(float4*)&Wgp[(size_t)jb * 65536 + (size_t)bh * 1024 +
                       (wv + 4 * k) * 16 + hi * 4] = o;   // FIXED address
      }
      a0 = n0v; a1 = n1v;
    }
  }
}

// ---------------------------------------------------------------------------
// K3: out = (V .* w) @ Wob^T; w = sum of 8 partials (2KB LDS prologue).
// 512 blocks x 256; M-tile 64, N-tile 64; main loop barrier-free.
// ---------------------------------------------------------------------------
__global__ __launch_bounds__(256, 2) void k_out(
    const short* __restrict__ Vh, const float* __restrict__ Wgp,
    const short* __restrict__ Wob, float* __restrict__ Out)
{
  __shared__ float Wl[8][64];
  const int hw = blockIdx.x, t = threadIdx.x;
  const int slot = hw >> 3;
  const int g    = (hw & 7) * 16 + (slot >> 2);
  const int nt   = slot & 3;
  const int b    = g >> 4;
  const int mt   = g & 15;
  const int n0   = nt * 64;
  const int m0   = mt * 64;
  const int wv = t >> 6, l = t & 63, lo = l & 15, hi = l >> 4;

  // prologue: sum the 8 jb-partials for this block's 64 rows x 8 heads
#pragma unroll
  for (int e = t; e < 512; e += 256) {
    int s = e >> 6, i2 = e & 63;
    float sum = 0.f;
#pragma unroll
    for (int p = 0; p < 8; ++p)
      sum += Wgp[(size_t)p * 65536 + (size_t)(b * 8 + s) * 1024 + m0 + i2];
    Wl[s][i2] = sum;
  }
  __syncthreads();

  f32x4 acc[4];
#pragma unroll
  for (int j = 0; j < 4; ++j) acc[j] = (f32x4){0.f, 0.f, 0.f, 0.f};

#pragma unroll 1
  for (int s = 0; s < 8; ++s) {
    const float w = Wl[s][wv * 16 + lo];
    const short* vr = Vh + (size_t)(b * 8 + s) * 65536 +
                      (size_t)(m0 + wv * 16 + lo) * 64 + hi * 8;
#pragma unroll
    for (int kk = 0; kk < 2; ++kk) {
      int4 raw = *(const int4*)(vr + kk * 32);
      uint32_t* u = (uint32_t*)&raw;
      uint32_t o[4];
#pragma unroll
      for (int j = 0; j < 4; ++j) {
        float f0 = __uint_as_float(u[j] << 16) * w;
        float f1 = __uint_as_float(u[j] & 0xffff0000u) * w;
        o[j] = pk2(f0, f1);
      }
      bf16x8 a = *(bf16x8*)o;
#pragma unroll
      for (int fc = 0; fc < 4; ++fc) {
        bf16x8 bfr = *(const bf16x8*)(Wob + (size_t)(n0 + fc * 16 + lo) * 512 +
                                      s * 64 + kk * 32 + hi * 8);
        acc[fc] = MFMA(a, bfr, acc[fc]);
      }
    }
  }

#pragma unroll
  for (int fc = 0; fc < 4; ++fc)
#pragma unroll
    for (int r = 0; r < 4; ++r) {
      int i = m0 + wv * 16 + hi * 4 + r;
      int o = n0 + fc * 16 + lo;
      Out[(size_t)(b * 1024 + i) * 256 + o] = acc[fc][r];
    }
}

// ---------------------------------------------------------------------------
extern "C" void kernel_launch(void* const* d_in, const int* in_sizes, int n_in,
                              void* d_out, int out_size, void* d_ws, size_t ws_size,
                              hipStream_t stream) {
  const float* F  = (const float*)d_in[0];
  const float* Wq = (const float*)d_in[1];
  const float* Wk = (const float*)d_in[2];
  const float* Wv = (const float*)d_in[3];
  const float* Wo = (const float*)d_in[4];
  float* out = (float*)d_out;

  char* ws = (char*)d_ws;
  short* Qh  = (short*)(ws);                                      // 8 MB bf16
  short* Kh  = (short*)(ws + (size_t)(8  << 20));                 // 8 MB
  short* Vh  = (short*)(ws + (size_t)(16 << 20));                 // 8 MB
  float* Wgp = (float*)(ws + (size_t)(24 << 20));                 // 2 MB
  short* Wt  = (short*)(ws + (size_t)(26 << 20));                 // 768 KB
  short* Wob = (short*)(ws + (size_t)(26 << 20) + (768 << 10));   // 256 KB

  k_prep<<<dim3(256), 256, 0, stream>>>(Wq, Wk, Wv, Wo, Wt, Wob);
  k_qkv <<<dim3(512), 256, 0, stream>>>(F, Wt, Qh, Kh, Vh);
  k_attw<<<dim3(512), 256, 0, stream>>>(Qh, Kh, Wgp);
  k_out <<<dim3(512), 256, 0, stream>>>(Vh, Wgp, Wob, out);
}

// Round 11
// 96.074 us; speedup vs baseline: 1.5452x; 1.0583x over previous
//
#include <hip/hip_runtime.h>
#include <hip/hip_bf16.h>
#include <cstdint>

// Problem: B=8, N=1024, C=256, H=8, D=64.
// out[b,i,o] = sum_{h,d} V[b,i,h,d] * w[b,i,h] * Wout[o,h,d]
// w[b,i,h]   = sum_j exp(S_ij)/d_j ;  S = Q K^T / 8 ; d_j = sum_i exp(S_ij)
// Wq pre-scaled by 0.125*log2(e) in prep => exp(S/8) == exp2(Q'K^T).
//
// Barrier-free design: MFMA fragments per-lane from global (L2-resident).
//  k_prep: Wt[3][512][256] bf16 (transposed, Q-scaled) + Wob[256][512] bf16.
//  k_qkv : 512 blocks, 0 barriers; co-XCD groups share the F slice.
//  k_attw: 512 blocks = (bh co-XCD x 8 jb); K-slice resident in regs;
//          2-strip-per-iteration ILP; ONE barrier (cross-wave d_j reduce).
//  k_out : 512 blocks, w-partial sum in 2KB LDS prologue (one barrier).
// Layouts: Qh/Kh/Vh=[b*8+h][i][d] bf16; Wgp=[jb][b*8+h][i] f32.

typedef __attribute__((ext_vector_type(8))) short bf16x8;
typedef __attribute__((ext_vector_type(4))) float f32x4;

#define EXP2(x) __builtin_amdgcn_exp2f(x)
#define MFMA(a, b, c) __builtin_amdgcn_mfma_f32_16x16x32_bf16((a), (b), (c), 0, 0, 0)
#define QSCALE 0.18033688011112042f

static __device__ __forceinline__ uint32_t pk2(float x, float y) {
  union { __hip_bfloat162 h; uint32_t u; } c;
  c.h = __float22bfloat162_rn(float2{x, y});
  return c.u;
}
static __device__ __forceinline__ short cvt1(float f) {
  union { __hip_bfloat16 h; short s; } c;
  c.h = __float2bfloat16(f);
  return c.s;
}
static __device__ __forceinline__ bf16x8 mk8(const float4& u, const float4& v) {
  union { bf16x8 b; uint32_t w[4]; } r;
  r.w[0] = pk2(u.x, u.y); r.w[1] = pk2(u.z, u.w);
  r.w[2] = pk2(v.x, v.y); r.w[3] = pk2(v.z, v.w);
  return r.b;
}

// ---------------------------------------------------------------------------
// K0: weight prep. Wt[m][n][c] = bf16(W_m[c][n] * (m==0?QSCALE:1)),
// Wob[o][k] = bf16(Wo[o][k]). 256 blocks x 256.
// ---------------------------------------------------------------------------
__global__ __launch_bounds__(256) void k_prep(
    const float* __restrict__ Wq, const float* __restrict__ Wk,
    const float* __restrict__ Wv, const float* __restrict__ Wo,
    short* __restrict__ Wt, short* __restrict__ Wob)
{
  const int gt = blockIdx.x * 256 + threadIdx.x;
  if (gt < 49152) {
    const int m  = gt >> 14;
    const int r  = gt & 16383;
    const int n  = r >> 5;     // 0..511
    const int c8 = r & 31;     // c = c8*8
    const float* W = (m == 0) ? Wq : (m == 1) ? Wk : Wv;
    const float scale = (m == 0) ? QSCALE : 1.0f;
    short tmp[8];
#pragma unroll
    for (int j = 0; j < 8; ++j)
      tmp[j] = cvt1(W[(size_t)(c8 * 8 + j) * 512 + n] * scale);
    *(int4*)&Wt[(size_t)m * 131072 + n * 256 + c8 * 8] = *(int4*)tmp;
  } else if (gt < 65536) {
    const int r  = gt - 49152; // 0..16383
    const int o  = r >> 6;
    const int k8 = r & 63;
    const float4 v0 = *(const float4*)(Wo + (size_t)o * 512 + k8 * 8);
    const float4 v1 = *(const float4*)(Wo + (size_t)o * 512 + k8 * 8 + 4);
    uint32_t tmp[4] = {pk2(v0.x, v0.y), pk2(v0.z, v0.w),
                       pk2(v1.x, v1.y), pk2(v1.z, v1.w)};
    *(uint4*)&Wob[(size_t)o * 512 + k8 * 8] = *(uint4*)tmp;
  }
}

// ---------------------------------------------------------------------------
// K1: fused QKV projection. 512 blocks x 256, ZERO barriers / no LDS.
// XCD decode: xcd = hw&7; the 8 h-blocks of one (b,mt) F-slice co-locate
// on ONE XCD (slice 128 KB; 8 slices/XCD = 1 MB + Wt 768 KB in L2).
// ---------------------------------------------------------------------------
__global__ __launch_bounds__(256, 2) void k_qkv(
    const float* __restrict__ F, const short* __restrict__ Wt,
    short* __restrict__ Qh, short* __restrict__ Kh, short* __restrict__ Vh)
{
  const int hw = blockIdx.x, t = threadIdx.x;
  const int xcd  = hw & 7;
  const int slot = hw >> 3;            // 0..63
  const int g    = xcd * 8 + (slot >> 3);  // (b,mt) group, co-XCD
  const int h    = slot & 7;
  const int b    = g >> 3;
  const int mt   = g & 7;
  const int n0 = h * 64, m0 = mt * 128;
  const int wv = t >> 6, l = t & 63, lo = l & 15, hi = l >> 4;

  f32x4 acc[3][2][4];
#pragma unroll
  for (int m = 0; m < 3; ++m)
#pragma unroll
    for (int i = 0; i < 2; ++i)
#pragma unroll
      for (int j = 0; j < 4; ++j) acc[m][i][j] = (f32x4){0.f, 0.f, 0.f, 0.f};

  const float* arow0 = F + (size_t)(b * 1024 + m0 + wv * 32 + lo) * 256;
  const float* arow1 = F + (size_t)(b * 1024 + m0 + wv * 32 + 16 + lo) * 256;

#pragma unroll 1
  for (int s = 0; s < 4; ++s) {
    const int k0 = s * 64;
    // A fragments: fp32 -> bf16 in registers, per-lane loads
    bf16x8 a[2][2];
#pragma unroll
    for (int kk = 0; kk < 2; ++kk) {
      const int off = k0 + kk * 32 + hi * 8;
      a[0][kk] = mk8(*(const float4*)(arow0 + off), *(const float4*)(arow0 + off + 4));
      a[1][kk] = mk8(*(const float4*)(arow1 + off), *(const float4*)(arow1 + off + 4));
    }
    // B fragments per-lane from Wt (L2-hot: co-XCD blocks share panel)
#pragma unroll
    for (int m = 0; m < 3; ++m)
#pragma unroll
      for (int kk = 0; kk < 2; ++kk)
#pragma unroll
        for (int fc = 0; fc < 4; ++fc) {
          bf16x8 bfr = *(const bf16x8*)(Wt + (size_t)m * 131072 +
                         (size_t)(n0 + fc * 16 + lo) * 256 + k0 + kk * 32 + hi * 8);
          acc[m][0][fc] = MFMA(a[0][kk], bfr, acc[m][0][fc]);
          acc[m][1][fc] = MFMA(a[1][kk], bfr, acc[m][1][fc]);
        }
  }

#pragma unroll
  for (int m = 0; m < 3; ++m) {
    short* O = (m == 0) ? Qh : (m == 1) ? Kh : Vh;
#pragma unroll
    for (int fr = 0; fr < 2; ++fr)
#pragma unroll
      for (int fc = 0; fc < 4; ++fc)
#pragma unroll
        for (int r = 0; r < 4; ++r) {
          int i = m0 + wv * 32 + fr * 16 + hi * 4 + r;
          int d = fc * 16 + lo;
          O[((size_t)(b * 8 + h) * 1024 + i) * 64 + d] = cvt1(acc[m][fr][fc][r]);
        }
  }
}

// ---------------------------------------------------------------------------
// K2: fused colsum+rowsum. 512 blocks = (bh co-XCD) x 8 jb (128 j each).
// K-slice resident in regs; each iteration processes TWO i-strips (ILP).
// ONE barrier total (cross-wave d_j reduce).
// ---------------------------------------------------------------------------
__global__ __launch_bounds__(256, 2) void k_attw(
    const short* __restrict__ Qh, const short* __restrict__ Kh,
    float* __restrict__ Wgp)
{
  __shared__ float Red[512];
  const int hw = blockIdx.x, t = threadIdx.x;
  const int xcd = hw & 7;
  const int idx = hw >> 3;              // 0..63
  const int bh  = xcd * 8 + (idx >> 3); // same-bh blocks co-XCD
  const int jb  = idx & 7;
  const size_t base = (size_t)bh * 65536;
  const int j0 = jb * 128;
  const int wv = t >> 6, l = t & 63, lo = l & 15, hi = l >> 4;
  const short* qbase = Qh + base + (size_t)lo * 64 + hi * 8;

  // resident K fragments: 8 strips of 16 j per wave (all 128 j of the slice)
  bf16x8 bk[8][2];
#pragma unroll
  for (int js = 0; js < 8; ++js) {
    const short* kr = Kh + base + (size_t)(j0 + js * 16 + lo) * 64 + hi * 8;
    bk[js][0] = *(const bf16x8*)(kr);
    bk[js][1] = *(const bf16x8*)(kr + 32);
  }

  // -------- pass 1: d_j = sum_i exp2(S'_ij); wave wv: strip pairs (wv+8k, wv+8k+4)
  float cs[8];
#pragma unroll
  for (int js = 0; js < 8; ++js) cs[js] = 0.f;

  {
    bf16x8 a0[2], a1[2];
#pragma unroll
    for (int p = 0; p < 2; ++p) {
      const short* q = qbase + (size_t)(wv + 4 * p) * 16 * 64;
      a0[p] = *(const bf16x8*)(q);
      a1[p] = *(const bf16x8*)(q + 32);
    }
#pragma unroll 1
    for (int k = 0; k < 8; ++k) {
      bf16x8 n0[2], n1[2];
      if (k < 7) {
#pragma unroll
        for (int p = 0; p < 2; ++p) {
          const short* q = qbase + (size_t)(wv + 8 * (k + 1) + 4 * p) * 16 * 64;
          n0[p] = *(const bf16x8*)(q);
          n1[p] = *(const bf16x8*)(q + 32);
        }
      }
#pragma unroll
      for (int js = 0; js < 8; ++js) {
#pragma unroll
        for (int p = 0; p < 2; ++p) {
          f32x4 acc = (f32x4){0.f, 0.f, 0.f, 0.f};
          acc = MFMA(a0[p], bk[js][0], acc);
          acc = MFMA(a1[p], bk[js][1], acc);
#pragma unroll
          for (int r = 0; r < 4; ++r) cs[js] += EXP2(acc[r]);
        }
      }
      if (k < 7) {
#pragma unroll
        for (int p = 0; p < 2; ++p) { a0[p] = n0[p]; a1[p] = n1[p]; }
      }
    }
  }

#pragma unroll
  for (int js = 0; js < 8; ++js) {
    cs[js] += __shfl_xor(cs[js], 16, 64);
    cs[js] += __shfl_xor(cs[js], 32, 64);
  }
  if (hi == 0) {
#pragma unroll
    for (int js = 0; js < 8; ++js) Red[wv * 128 + js * 16 + lo] = cs[js];
  }
  __syncthreads();   // the only barrier
  float rj[8];
#pragma unroll
  for (int js = 0; js < 8; ++js) {
    int jj = js * 16 + lo;
    float d = Red[jj] + Red[128 + jj] + Red[256 + jj] + Red[384 + jj];
    rj[js] = __builtin_amdgcn_rcpf(d);
  }

  // -------- pass 2: partial w_i over this j-slice (2 strips / iteration)
  {
    bf16x8 a0[2], a1[2];
#pragma unroll
    for (int p = 0; p < 2; ++p) {
      const short* q = qbase + (size_t)(wv + 4 * p) * 16 * 64;
      a0[p] = *(const bf16x8*)(q);
      a1[p] = *(const bf16x8*)(q + 32);
    }
#pragma unroll 1
    for (int k = 0; k < 8; ++k) {
      bf16x8 n0[2], n1[2];
      if (k < 7) {
#pragma unroll
        for (int p = 0; p < 2; ++p) {
          const short* q = qbase + (size_t)(wv + 8 * (k + 1) + 4 * p) * 16 * 64;
          n0[p] = *(const bf16x8*)(q);
          n1[p] = *(const bf16x8*)(q + 32);
        }
      }
      float ws4[2][4] = {{0.f, 0.f, 0.f, 0.f}, {0.f, 0.f, 0.f, 0.f}};
#pragma unroll
      for (int js = 0; js < 8; ++js) {
#pragma unroll
        for (int p = 0; p < 2; ++p) {
          f32x4 acc = (f32x4){0.f, 0.f, 0.f, 0.f};
          acc = MFMA(a0[p], bk[js][0], acc);
          acc = MFMA(a1[p], bk[js][1], acc);
#pragma unroll
          for (int r = 0; r < 4; ++r) ws4[p][r] = fmaf(EXP2(acc[r]), rj[js], ws4[p][r]);
        }
      }
#pragma unroll
      for (int m = 1; m <= 8; m <<= 1)
#pragma unroll
        for (int p = 0; p < 2; ++p)
#pragma unroll
          for (int r = 0; r < 4; ++r) ws4[p][r] += __shfl_xor(ws4[p][r], m, 64);
      if (lo == 0) {
#pragma unroll
        for (int p = 0; p < 2; ++p) {
          float4 o = {ws4[p][0], ws4[p][1], ws4[p][2], ws4[p][3]};
          *(float4*)&Wgp[(size_t)jb * 65536 + (size_t)bh * 1024 +
                         (wv + 8 * k + 4 * p) * 16 + hi * 4] = o;
        }
      }
      if (k < 7) {
#pragma unroll
        for (int p = 0; p < 2; ++p) { a0[p] = n0[p]; a1[p] = n1[p]; }
      }
    }
  }
}

// ---------------------------------------------------------------------------
// K3: out = (V .* w) @ Wob^T; w = sum of 8 partials (2KB LDS prologue).
// 512 blocks x 256; M-tile 64, N-tile 64; main loop barrier-free.
// ---------------------------------------------------------------------------
__global__ __launch_bounds__(256, 2) void k_out(
    const short* __restrict__ Vh, const float* __restrict__ Wgp,
    const short* __restrict__ Wob, float* __restrict__ Out)
{
  __shared__ float Wl[8][64];
  const int hw = blockIdx.x, t = threadIdx.x;
  const int slot = hw >> 3;
  const int g    = (hw & 7) * 16 + (slot >> 2);
  const int nt   = slot & 3;
  const int b    = g >> 4;
  const int mt   = g & 15;
  const int n0   = nt * 64;
  const int m0   = mt * 64;
  const int wv = t >> 6, l = t & 63, lo = l & 15, hi = l >> 4;

  // prologue: sum the 8 jb-partials for this block's 64 rows x 8 heads
#pragma unroll
  for (int e = t; e < 512; e += 256) {
    int s = e >> 6, i2 = e & 63;
    float sum = 0.f;
#pragma unroll
    for (int p = 0; p < 8; ++p)
      sum += Wgp[(size_t)p * 65536 + (size_t)(b * 8 + s) * 1024 + m0 + i2];
    Wl[s][i2] = sum;
  }
  __syncthreads();

  f32x4 acc[4];
#pragma unroll
  for (int j = 0; j < 4; ++j) acc[j] = (f32x4){0.f, 0.f, 0.f, 0.f};

#pragma unroll 1
  for (int s = 0; s < 8; ++s) {
    const float w = Wl[s][wv * 16 + lo];
    const short* vr = Vh + (size_t)(b * 8 + s) * 65536 +
                      (size_t)(m0 + wv * 16 + lo) * 64 + hi * 8;
#pragma unroll
    for (int kk = 0; kk < 2; ++kk) {
      int4 raw = *(const int4*)(vr + kk * 32);
      uint32_t* u = (uint32_t*)&raw;
      uint32_t o[4];
#pragma unroll
      for (int j = 0; j < 4; ++j) {
        float f0 = __uint_as_float(u[j] << 16) * w;
        float f1 = __uint_as_float(u[j] & 0xffff0000u) * w;
        o[j] = pk2(f0, f1);
      }
      bf16x8 a = *(bf16x8*)o;
#pragma unroll
      for (int fc = 0; fc < 4; ++fc) {
        bf16x8 bfr = *(const bf16x8*)(Wob + (size_t)(n0 + fc * 16 + lo) * 512 +
                                      s * 64 + kk * 32 + hi * 8);
        acc[fc] = MFMA(a, bfr, acc[fc]);
      }
    }
  }

#pragma unroll
  for (int fc = 0; fc < 4; ++fc)
#pragma unroll
    for (int r = 0; r < 4; ++r) {
      int i = m0 + wv * 16 + hi * 4 + r;
      int o = n0 + fc * 16 + lo;
      Out[(size_t)(b * 1024 + i) * 256 + o] = acc[fc][r];
    }
}

// ---------------------------------------------------------------------------
extern "C" void kernel_launch(void* const* d_in, const int* in_sizes, int n_in,
                              void* d_out, int out_size, void* d_ws, size_t ws_size,
                              hipStream_t stream) {
  const float* F  = (const float*)d_in[0];
  const float* Wq = (const float*)d_in[1];
  const float* Wk = (const float*)d_in[2];
  const float* Wv = (const float*)d_in[3];
  const float* Wo = (const float*)d_in[4];
  float* out = (float*)d_out;

  char* ws = (char*)d_ws;
  short* Qh  = (short*)(ws);                                      // 8 MB bf16
  short* Kh  = (short*)(ws + (size_t)(8  << 20));                 // 8 MB
  short* Vh  = (short*)(ws + (size_t)(16 << 20));                 // 8 MB
  float* Wgp = (float*)(ws + (size_t)(24 << 20));                 // 2 MB
  short* Wt  = (short*)(ws + (size_t)(26 << 20));                 // 768 KB
  short* Wob = (short*)(ws + (size_t)(26 << 20) + (768 << 10));   // 256 KB

  k_prep<<<dim3(256), 256, 0, stream>>>(Wq, Wk, Wv, Wo, Wt, Wob);
  k_qkv <<<dim3(512), 256, 0, stream>>>(F, Wt, Qh, Kh, Vh);
  k_attw<<<dim3(512), 256, 0, stream>>>(Qh, Kh, Wgp);
  k_out <<<dim3(512), 256, 0, stream>>>(Vh, Wgp, Wob, out);
}